// Round 7
// baseline (78.076 us; speedup 1.0000x reference)
//
#include <hip/hip_runtime.h>
#include <stdint.h>

typedef __attribute__((ext_vector_type(8))) short bf16x8;
typedef __attribute__((ext_vector_type(4))) float f32x4;
typedef unsigned short ushort_t;

#define NE 6291456   // 8*1024*12*64 elements (one QKV-sized bf16 buffer)

__device__ __forceinline__ unsigned short f2bf(float f){
  union { float f; unsigned u; } c; c.f = f;
  unsigned u = c.u;
  u = u + 0x7FFFu + ((u >> 16) & 1u);
  return (unsigned short)(u >> 16);
}

__device__ __forceinline__ float bfh2f(ushort_t u){
  union { unsigned u; float f; } c; c.u = ((unsigned)u) << 16; return c.f;
}

__device__ __forceinline__ bf16x8 cvt8(const float* p){
  const float4 a = ((const float4*)p)[0];
  const float4 b = ((const float4*)p)[1];
  bf16x8 r;
  r[0]=(short)f2bf(a.x); r[1]=(short)f2bf(a.y); r[2]=(short)f2bf(a.z); r[3]=(short)f2bf(a.w);
  r[4]=(short)f2bf(b.x); r[5]=(short)f2bf(b.y); r[6]=(short)f2bf(b.z); r[7]=(short)f2bf(b.w);
  return r;
}

__device__ __forceinline__ uint32_t pk2bf(float a, float b){
  uint32_t r;
  asm("v_cvt_pk_bf16_f32 %0, %1, %2" : "=v"(r) : "v"(a), "v"(b));
  return r;
}

__device__ __forceinline__ float exp2x(float x){
  float r;
  asm("v_exp_f32 %0, %1" : "=v"(r) : "v"(x));
  return r;
}

__device__ __forceinline__ void gll16(const ushort_t* g, short* l){
  __builtin_amdgcn_global_load_lds(
      (const __attribute__((address_space(1))) unsigned int*)g,
      (__attribute__((address_space(3))) unsigned int*)l, 16, 0, 0);
}

// rr (0..11) -> key index, dx, d
__device__ __forceinline__ void rr_decode(int rr, int& i, int& dx, int& d){
  if (rr < 2){ i = rr; dx = 0; d = 1; }
  else { i = 2 + ((rr-2)>>1); dx = (rr-2)&1; d = 2; }
}

// ---------------- Kernel 0: weight pre-convert f32 -> bf16 ----------------
__global__ __launch_bounds__(256) void wconv(
    const float* __restrict__ Wq, const float* __restrict__ Wk,
    const float* __restrict__ Wv, const float* __restrict__ Wo,
    ushort_t* __restrict__ out)
{
  const int a = blockIdx.y;
  const float* src = (a==0)?Wq:(a==1)?Wk:(a==2)?Wv:Wo;
  const float sc = (a==0) ? 0.14724743479535623f : 1.0f;  // log2(e)/sqrt(96)
  const int i = (blockIdx.x*256 + threadIdx.x)*8;
  float4 v0 = *(const float4*)(src+i);
  float4 v1 = *(const float4*)(src+i+4);
  uint4 o;
  o.x = pk2bf(v0.x*sc, v0.y*sc);
  o.y = pk2bf(v0.z*sc, v0.w*sc);
  o.z = pk2bf(v1.x*sc, v1.y*sc);
  o.w = pk2bf(v1.z*sc, v1.w*sc);
  *(uint4*)(out + (size_t)a*28672 + i) = o;
}

// ---------------- Kernel A: QKV projection ----------------
// Block = (rr, 64 bs-rows). Q,K: C^T-form MFMA -> register-direct 8B frag-order
// stores. V: LDS transpose path (pi-permuted kv slots).
__global__ __launch_bounds__(256) void qkv_proj(
    const float* __restrict__ xA1, const float* __restrict__ xB2,
    const float* __restrict__ xE1, const float* __restrict__ xE2,
    const float* __restrict__ xE3, const float* __restrict__ xE4,
    const float* __restrict__ xE5,
    const ushort_t* __restrict__ Wb4,
    ushort_t* __restrict__ Qg, ushort_t* __restrict__ Kg,
    ushort_t* __restrict__ Vg)
{
  __shared__ short Cl[64*72];            // V out tile [64 s][64 o], stride 72

  const int tile = blockIdx.x;           // 0..1535
  const int rr = tile >> 7, rt = tile & 127;
  int i, dx, d; rr_decode(rr, i, dx, d);
  const float* xp = (i==0)?xA1:(i==1)?xB2:(i==2)?xE1:(i==3)?xE2:(i==4)?xE3:(i==5)?xE4:xE5;

  const int lane = threadIdx.x & 63;
  const int w    = threadIdx.x >> 6;
  const int lo = lane & 15, hi = lane >> 4;
  const int b8 = (rt >> 4) * 8;
  const int tile64 = rt & 15;

  bf16x8 afr[2];
  {
    const int R = rt*64 + w*16 + lo;
    const float* rp = xp + (size_t)(R*d + dx) * 64;
    afr[0] = cvt8(rp + 8*hi);
    afr[1] = cvt8(rp + 32 + 8*hi);
  }

  // ---- Q, K: C^T form, register-direct stores ----
  ushort_t* OgQK[2] = {Qg, Kg};
  #pragma unroll
  for (int wsel = 0; wsel < 2; ++wsel){
    const ushort_t* Wb = Wb4 + (size_t)wsel*28672 + (size_t)i * 4096;
    #pragma unroll
    for (int ot = 0; ot < 4; ++ot){
      f32x4 acc = {0.f,0.f,0.f,0.f};
      #pragma unroll
      for (int c = 0; c < 2; ++c){
        bf16x8 bfr = *(const bf16x8*)(Wb + (size_t)(lo + 16*ot) * 64 + 32*c + 8*hi);
        acc = __builtin_amdgcn_mfma_f32_16x16x32_bf16(bfr, afr[c], acc, 0, 0, 0);
      }
      // lane holds C^T[o = 16ot+4hi+r][s-col = w*16+lo], r=0..3 (4 consecutive mm)
      uint2 o2;
      o2.x = pk2bf(acc[0], acc[1]);
      o2.y = pk2bf(acc[2], acc[3]);
      int hh = 2*ot + (hi>>1);
      size_t a = (size_t)((b8 + hh)*16 + tile64)*6144
               + (size_t)((w*3 + (rr>>2))*64 + (rr&3)*16 + lo)*8 + 4*(hi&1);
      *(uint2*)(OgQK[wsel] + a) = o2;
    }
  }

  // ---- V: via LDS permute path ----
  {
    const ushort_t* Wb = Wb4 + (size_t)2*28672 + (size_t)i * 4096;
    #pragma unroll
    for (int ot = 0; ot < 4; ++ot){
      f32x4 acc = {0.f,0.f,0.f,0.f};
      #pragma unroll
      for (int c = 0; c < 2; ++c){
        bf16x8 bfr = *(const bf16x8*)(Wb + (size_t)(lo + 16*ot) * 64 + 32*c + 8*hi);
        acc = __builtin_amdgcn_mfma_f32_16x16x32_bf16(afr[c], bfr, acc, 0, 0, 0);
      }
      #pragma unroll
      for (int r = 0; r < 4; ++r)
        Cl[(w*16 + hi*4 + r)*72 + lo + 16*ot] = (short)f2bf(acc[r]);
    }
    __syncthreads();
    #pragma unroll
    for (int cc = 0; cc < 2; ++cc){
      int c2 = threadIdx.x + cc*256;
      int mm = c2 & 7, hh = (c2>>3)&7, sblk = c2>>6;
      int a5 = sblk>>2, slot = sblk&3;
      short tmp[8];
      #pragma unroll
      for (int jj = 0; jj < 8; ++jj){
        int s_j = a5*32 + (jj>>2)*16 + slot*4 + (jj&3);
        tmp[jj] = Cl[s_j*72 + hh*8 + mm];
      }
      int fh = rr>>1, fl = (rr&1)*8 + mm;
      size_t a = (size_t)((b8 + hh)*16 + tile64)*6144
               + (size_t)((a5*6 + fh)*64 + slot*16 + fl)*8;
      *(bf16x8*)(Vg + a) = *(const bf16x8*)tmp;
    }
  }
}

// ---------------- Kernel B: flash attention (no-max, kv-split x2) ----------------
// grid 1024: xcd=bid&7, bh=xcd*8+((bid>>3)&7), v=bid>>6: qt=v>>1 (q-tile 128),
// kvh=v&1 (kv half). 4 waves x 32 q (g=2). 8 KV tiles of 64, double-buffered.
// Writes UNNORMALIZED O-partial (bf16) + l (f32); out_proj combines halves.
__global__ __launch_bounds__(256, 3) void attn(
    const ushort_t* __restrict__ Qg,
    const ushort_t* __restrict__ Kg,
    const ushort_t* __restrict__ Vg,
    ushort_t* __restrict__ Op,       // [2][NE] partials
    float* __restrict__ Lb)          // [2][64][1024]
{
  __shared__ __align__(16) short Kl[2][6144];
  __shared__ __align__(16) short Vl[2][6144];

  const int bid = blockIdx.x;
  const int bh = (bid & 7)*8 + ((bid >> 3) & 7);
  const int vv = bid >> 6;                      // 0..15
  const int qt = vv >> 1, kvh = vv & 1;
  const int tid = threadIdx.x;
  const int w = tid >> 6, lane = tid & 63;
  const int lo = lane & 15, hi = lane >> 4;
  const size_t base = (size_t)bh * 16 * 6144;
  const int tbase = kvh * 8;

  bf16x8 qf[2][3];
  #pragma unroll
  for (int g = 0; g < 2; ++g){
    int qq = qt*128 + w*32 + g*16;
    const ushort_t* qb = Qg + base + (size_t)(qq >> 6)*6144 + (size_t)(((qq>>4)&3)*3)*512;
    #pragma unroll
    for (int c = 0; c < 3; ++c)
      qf[g][c] = *(const bf16x8*)(qb + (c*64 + lane)*8);
  }

  f32x4 acc[6][2];
  #pragma unroll
  for (int ft = 0; ft < 6; ++ft){ acc[ft][0] = (f32x4){0,0,0,0}; acc[ft][1] = (f32x4){0,0,0,0}; }
  float lr[2] = {0.f, 0.f};

#define STAGE(tt, bb) do { \
    const ushort_t* kg_ = Kg + base + (size_t)(tt)*6144 + tid*8; \
    const ushort_t* vg_ = Vg + base + (size_t)(tt)*6144 + tid*8; \
    short* kl_ = &Kl[bb][tid*8]; short* vl_ = &Vl[bb][tid*8]; \
    gll16(kg_,        kl_);        gll16(kg_ + 2048, kl_ + 2048); \
    gll16(kg_ + 4096, kl_ + 4096); gll16(vg_,        vl_); \
    gll16(vg_ + 2048, vl_ + 2048); gll16(vg_ + 4096, vl_ + 4096); \
  } while(0)

  STAGE(tbase, 0);
  __syncthreads();

  for (int t = 0; t < 8; ++t){
    if (t < 7) STAGE(tbase + t + 1, (t+1)&1);
    const int cb = t & 1;

    // QK^T (swapped): st[g][kvb][r] = S^T[kv=16kvb+4hi+r][q]
    f32x4 st[2][4];
    __builtin_amdgcn_s_setprio(1);
    #pragma unroll
    for (int kvb = 0; kvb < 4; ++kvb){
      bf16x8 kf[3];
      #pragma unroll
      for (int c = 0; c < 3; ++c)
        kf[c] = *(const bf16x8*)&Kl[cb][((kvb*3 + c)*64 + lane)*8];
      #pragma unroll
      for (int g = 0; g < 2; ++g){
        f32x4 s = {0.f,0.f,0.f,0.f};
        #pragma unroll
        for (int c = 0; c < 3; ++c)
          s = __builtin_amdgcn_mfma_f32_16x16x32_bf16(kf[c], qf[g][c], s, 0, 0, 0);
        st[g][kvb] = s;
      }
    }
    __builtin_amdgcn_s_setprio(0);

    // no-max softmax: p = exp2(s); lane-partial denominator
    bf16x8 pb[2][2];
    #pragma unroll
    for (int g = 0; g < 2; ++g){
      #pragma unroll
      for (int kvb = 0; kvb < 4; ++kvb)
        #pragma unroll
        for (int r = 0; r < 4; ++r){ st[g][kvb][r] = exp2x(st[g][kvb][r]); lr[g] += st[g][kvb][r]; }
      #pragma unroll
      for (int ch = 0; ch < 2; ++ch){
        union { uint32_t u[4]; bf16x8 v; } pu;
        pu.u[0] = pk2bf(st[g][2*ch  ][0], st[g][2*ch  ][1]);
        pu.u[1] = pk2bf(st[g][2*ch  ][2], st[g][2*ch  ][3]);
        pu.u[2] = pk2bf(st[g][2*ch+1][0], st[g][2*ch+1][1]);
        pu.u[3] = pk2bf(st[g][2*ch+1][2], st[g][2*ch+1][3]);
        pb[g][ch] = pu.v;
      }
    }

    // PV
    __builtin_amdgcn_s_setprio(1);
    #pragma unroll
    for (int ch = 0; ch < 2; ++ch){
      #pragma unroll
      for (int ft = 0; ft < 6; ++ft){
        bf16x8 va = *(const bf16x8*)&Vl[cb][((ch*6 + ft)*64 + lane)*8];
        acc[ft][0] = __builtin_amdgcn_mfma_f32_16x16x32_bf16(va, pb[0][ch], acc[ft][0], 0, 0, 0);
        acc[ft][1] = __builtin_amdgcn_mfma_f32_16x16x32_bf16(va, pb[1][ch], acc[ft][1], 0, 0, 0);
      }
    }
    __builtin_amdgcn_s_setprio(0);

    __syncthreads();
  }
#undef STAGE

  // epilogue: store UNNORMALIZED partial + l
  ushort_t* Oph = Op + (size_t)kvh * NE;
  #pragma unroll
  for (int g = 0; g < 2; ++g){
    float l = lr[g];
    l += __shfl_xor(l, 16);
    l += __shfl_xor(l, 32);
    int q = qt*128 + w*32 + g*16 + lo;
    if (hi == 0) Lb[(size_t)(kvh*64 + bh)*1024 + q] = l;
    #pragma unroll
    for (int ft = 0; ft < 6; ++ft){
      uint2 o;
      o.x = pk2bf(acc[ft][g][0], acc[ft][g][1]);
      o.y = pk2bf(acc[ft][g][2], acc[ft][g][3]);
      size_t ad = ((size_t)(bh*24 + ft*4 + hi)*1024 + q)*4;
      *(uint2*)(Oph + ad) = o;
    }
  }
}

// ---------------- Kernel C: output projection (combines kv halves) ----------------
__global__ __launch_bounds__(256) void out_proj(
    const ushort_t* __restrict__ Op,     // [2][NE]
    const float* __restrict__ Lb,        // [2][64][1024]
    const ushort_t* __restrict__ Wb4,
    float* __restrict__ out)
{
  const int tile = blockIdx.x;
  const int rr = tile >> 7, rt = tile & 127;
  int i, dx, d; rr_decode(rr, i, dx, d); (void)dx; (void)d;

  const int lane = threadIdx.x & 63;
  const int w    = threadIdx.x >> 6;
  const int lo = lane & 15, hi = lane >> 4;

  const int R = rt*64 + w*16 + lo;
  const int b = R >> 10, s = R & 1023;

  bf16x8 afr[2];
  #pragma unroll
  for (int half = 0; half < 2; ++half){
    int bh = b*8 + half*4 + hi;
    float l0 = Lb[(size_t)bh*1024 + s];
    float l1 = Lb[(size_t)(64 + bh)*1024 + s];
    float rl = 1.f / (l0 + l1);
    union { uint2 u2[2]; ushort_t us[8]; } a0, a1;
    #pragma unroll
    for (int jj = 0; jj < 2; ++jj){
      size_t ad = ((size_t)(bh*24 + 2*rr + jj)*1024 + s)*4;
      a0.u2[jj] = *(const uint2*)(Op + ad);
      a1.u2[jj] = *(const uint2*)(Op + NE + ad);
    }
    union { uint32_t u[4]; bf16x8 v; } rv;
    #pragma unroll
    for (int e = 0; e < 4; ++e){
      float f0 = (bfh2f(a0.us[2*e])   + bfh2f(a1.us[2*e]))   * rl;
      float f1 = (bfh2f(a0.us[2*e+1]) + bfh2f(a1.us[2*e+1])) * rl;
      rv.u[e] = pk2bf(f0, f1);
    }
    afr[half] = rv.v;
  }

  const ushort_t* Wb = Wb4 + (size_t)3*28672 + (size_t)i * 4096;
  #pragma unroll
  for (int ot = 0; ot < 4; ++ot){
    f32x4 acc = {0.f,0.f,0.f,0.f};
    #pragma unroll
    for (int c = 0; c < 2; ++c){
      bf16x8 bfr = *(const bf16x8*)(Wb + (size_t)(lo + 16*ot) * 64 + 32*c + 8*hi);
      acc = __builtin_amdgcn_mfma_f32_16x16x32_bf16(afr[c], bfr, acc, 0, 0, 0);
    }
    #pragma unroll
    for (int r = 0; r < 4; ++r){
      int bs = rt*64 + w*16 + hi*4 + r;
      out[(size_t)(bs*12 + rr)*64 + lo + 16*ot] = acc[r];
    }
  }
}

extern "C" void kernel_launch(void* const* d_in, const int* in_sizes, int n_in,
                              void* d_out, int out_size, void* d_ws, size_t ws_size,
                              hipStream_t stream)
{
  const float* xA1 = (const float*)d_in[0];
  const float* xB2 = (const float*)d_in[1];
  const float* xE1 = (const float*)d_in[2];
  const float* xE2 = (const float*)d_in[3];
  const float* xE3 = (const float*)d_in[4];
  const float* xE4 = (const float*)d_in[5];
  const float* xE5 = (const float*)d_in[6];
  const float* Wq  = (const float*)d_in[7];
  const float* Wk  = (const float*)d_in[8];
  const float* Wv  = (const float*)d_in[9];
  const float* Wo  = (const float*)d_in[10];

  ushort_t* Qg  = (ushort_t*)d_ws;
  ushort_t* Kg  = Qg + NE;
  ushort_t* Vg  = Kg + NE;
  ushort_t* Op  = Vg + NE;                 // 2*NE partials
  ushort_t* Wb4 = Op + (size_t)2*NE;       // 4*28672 bf16
  float*    Lb  = (float*)(Wb4 + 4*28672); // 2*64*1024 f32

  wconv<<<dim3(14,4), dim3(256), 0, stream>>>(Wq, Wk, Wv, Wo, Wb4);
  qkv_proj<<<dim3(1536), dim3(256), 0, stream>>>(xA1,xB2,xE1,xE2,xE3,xE4,xE5,
                                                 Wb4, Qg,Kg,Vg);
  attn<<<dim3(1024), dim3(256), 0, stream>>>(Qg,Kg,Vg, Op, Lb);
  out_proj<<<dim3(1536), dim3(256), 0, stream>>>(Op, Lb, Wb4, (float*)d_out);
}

// Round 8
// 71.781 us; speedup vs baseline: 1.0877x; 1.0877x over previous
//
#include <hip/hip_runtime.h>
#include <stdint.h>

typedef __attribute__((ext_vector_type(8))) short bf16x8;
typedef __attribute__((ext_vector_type(4))) float f32x4;
typedef unsigned short ushort_t;

#define NE 6291456   // 8*1024*12*64 elements

__device__ __forceinline__ unsigned short f2bf(float f){
  union { float f; unsigned u; } c; c.f = f;
  unsigned u = c.u;
  u = u + 0x7FFFu + ((u >> 16) & 1u);
  return (unsigned short)(u >> 16);
}

__device__ __forceinline__ bf16x8 cvt8(const float* p){
  const float4 a = ((const float4*)p)[0];
  const float4 b = ((const float4*)p)[1];
  bf16x8 r;
  r[0]=(short)f2bf(a.x); r[1]=(short)f2bf(a.y); r[2]=(short)f2bf(a.z); r[3]=(short)f2bf(a.w);
  r[4]=(short)f2bf(b.x); r[5]=(short)f2bf(b.y); r[6]=(short)f2bf(b.z); r[7]=(short)f2bf(b.w);
  return r;
}

__device__ __forceinline__ uint32_t pk2bf(float a, float b){
  uint32_t r;
  asm("v_cvt_pk_bf16_f32 %0, %1, %2" : "=v"(r) : "v"(a), "v"(b));
  return r;
}

__device__ __forceinline__ float exp2x(float x){
  float r;
  asm("v_exp_f32 %0, %1" : "=v"(r) : "v"(x));
  return r;
}

__device__ __forceinline__ void gll16(const ushort_t* g, short* l){
  __builtin_amdgcn_global_load_lds(
      (const __attribute__((address_space(1))) unsigned int*)g,
      (__attribute__((address_space(3))) unsigned int*)l, 16, 0, 0);
}

// rr (0..11) -> key index, dx, d
__device__ __forceinline__ void rr_decode(int rr, int& i, int& dx, int& d){
  if (rr < 2){ i = rr; dx = 0; d = 1; }
  else { i = 2 + ((rr-2)>>1); dx = (rr-2)&1; d = 2; }
}

// ---------------- Kernel 0: weight pre-convert f32 -> bf16 ----------------
__global__ __launch_bounds__(256) void wconv(
    const float* __restrict__ Wq, const float* __restrict__ Wk,
    const float* __restrict__ Wv, const float* __restrict__ Wo,
    ushort_t* __restrict__ out)
{
  const int a = blockIdx.y;
  const float* src = (a==0)?Wq:(a==1)?Wk:(a==2)?Wv:Wo;
  const float sc = (a==0) ? 0.14724743479535623f : 1.0f;  // log2(e)/sqrt(96)
  const int i = (blockIdx.x*256 + threadIdx.x)*8;
  float4 v0 = *(const float4*)(src+i);
  float4 v1 = *(const float4*)(src+i+4);
  uint4 o;
  o.x = pk2bf(v0.x*sc, v0.y*sc);
  o.y = pk2bf(v0.z*sc, v0.w*sc);
  o.z = pk2bf(v1.x*sc, v1.y*sc);
  o.w = pk2bf(v1.z*sc, v1.w*sc);
  *(uint4*)(out + (size_t)a*28672 + i) = o;
}

// ---------------- Kernel A: QKV projection ----------------
// Block = (rr, 64 bs-rows). Q: register-direct C^T stores to Qg (64-s tiles).
// K,V: combined KVg buffer, 32-kv groups of 6144 shorts: [K 3072][V 3072].
//  K elem (s,rr,mm), s5=s&31: ((s5>>4)*3 + rr>>2)*64 + (rr&3)*16 + (s&15))*8 + mm
//  V elem (s,f=rr*8+mm): 3072 + ((f>>4)*64 + ((s5>>2)&3)*16 + (f&15))*8 + (s5&3)+4*(s5>>4)
__global__ __launch_bounds__(256) void qkv_proj(
    const float* __restrict__ xA1, const float* __restrict__ xB2,
    const float* __restrict__ xE1, const float* __restrict__ xE2,
    const float* __restrict__ xE3, const float* __restrict__ xE4,
    const float* __restrict__ xE5,
    const ushort_t* __restrict__ Wb4,
    ushort_t* __restrict__ Qg, ushort_t* __restrict__ KVg)
{
  __shared__ short Cl[64*72];            // V out tile [64 s][64 o], stride 72

  const int tile = blockIdx.x;           // 0..1535
  const int rr = tile >> 7, rt = tile & 127;
  int i, dx, d; rr_decode(rr, i, dx, d);
  const float* xp = (i==0)?xA1:(i==1)?xB2:(i==2)?xE1:(i==3)?xE2:(i==4)?xE3:(i==5)?xE4:xE5;

  const int lane = threadIdx.x & 63;
  const int w    = threadIdx.x >> 6;
  const int lo = lane & 15, hi = lane >> 4;
  const int b8 = (rt >> 4) * 8;
  const int tile64 = rt & 15;

  bf16x8 afr[2];
  {
    const int R = rt*64 + w*16 + lo;
    const float* rp = xp + (size_t)(R*d + dx) * 64;
    afr[0] = cvt8(rp + 8*hi);
    afr[1] = cvt8(rp + 32 + 8*hi);
  }

  // ---- Q: C^T form, register-direct stores (64-s tile layout) ----
  {
    const ushort_t* Wb = Wb4 + (size_t)i * 4096;
    #pragma unroll
    for (int ot = 0; ot < 4; ++ot){
      f32x4 acc = {0.f,0.f,0.f,0.f};
      #pragma unroll
      for (int c = 0; c < 2; ++c){
        bf16x8 bfr = *(const bf16x8*)(Wb + (size_t)(lo + 16*ot) * 64 + 32*c + 8*hi);
        acc = __builtin_amdgcn_mfma_f32_16x16x32_bf16(bfr, afr[c], acc, 0, 0, 0);
      }
      uint2 o2;
      o2.x = pk2bf(acc[0], acc[1]);
      o2.y = pk2bf(acc[2], acc[3]);
      int hh = 2*ot + (hi>>1);
      size_t a = (size_t)((b8 + hh)*16 + tile64)*6144
               + (size_t)((w*3 + (rr>>2))*64 + (rr&3)*16 + lo)*8 + 4*(hi&1);
      *(uint2*)(Qg + a) = o2;
    }
  }

  // ---- K: C^T form, register-direct stores (32-kv combined layout) ----
  {
    const ushort_t* Wb = Wb4 + (size_t)28672 + (size_t)i * 4096;
    #pragma unroll
    for (int ot = 0; ot < 4; ++ot){
      f32x4 acc = {0.f,0.f,0.f,0.f};
      #pragma unroll
      for (int c = 0; c < 2; ++c){
        bf16x8 bfr = *(const bf16x8*)(Wb + (size_t)(lo + 16*ot) * 64 + 32*c + 8*hi);
        acc = __builtin_amdgcn_mfma_f32_16x16x32_bf16(bfr, afr[c], acc, 0, 0, 0);
      }
      uint2 o2;
      o2.x = pk2bf(acc[0], acc[1]);
      o2.y = pk2bf(acc[2], acc[3]);
      int hh = 2*ot + (hi>>1);
      size_t a = (size_t)((b8 + hh)*32 + tile64*2 + (w>>1))*6144
               + (size_t)(((w&1)*3 + (rr>>2))*64 + (rr&3)*16 + lo)*8 + 4*(hi&1);
      *(uint2*)(KVg + a) = o2;
    }
  }

  // ---- V: via LDS permute path (pi-permuted kv slots) ----
  {
    const ushort_t* Wb = Wb4 + (size_t)2*28672 + (size_t)i * 4096;
    #pragma unroll
    for (int ot = 0; ot < 4; ++ot){
      f32x4 acc = {0.f,0.f,0.f,0.f};
      #pragma unroll
      for (int c = 0; c < 2; ++c){
        bf16x8 bfr = *(const bf16x8*)(Wb + (size_t)(lo + 16*ot) * 64 + 32*c + 8*hi);
        acc = __builtin_amdgcn_mfma_f32_16x16x32_bf16(afr[c], bfr, acc, 0, 0, 0);
      }
      #pragma unroll
      for (int r = 0; r < 4; ++r)
        Cl[(w*16 + hi*4 + r)*72 + lo + 16*ot] = (short)f2bf(acc[r]);
    }
    __syncthreads();
    #pragma unroll
    for (int cc = 0; cc < 2; ++cc){
      int c2 = threadIdx.x + cc*256;
      int mm = c2 & 7, hh = (c2>>3)&7, sblk = c2>>6;
      int a5 = sblk>>2, slot = sblk&3;
      short tmp[8];
      #pragma unroll
      for (int jj = 0; jj < 8; ++jj){
        int s_j = a5*32 + (jj>>2)*16 + slot*4 + (jj&3);
        tmp[jj] = Cl[s_j*72 + hh*8 + mm];
      }
      int fh = rr>>1, fl = (rr&1)*8 + mm;
      size_t a = (size_t)((b8 + hh)*32 + tile64*2 + a5)*6144 + 3072
               + (size_t)(fh*64 + slot*16 + fl)*8;
      *(bf16x8*)(KVg + a) = *(const bf16x8*)tmp;
    }
  }
}

// ---------------- Kernel B: flash attention (no-max, 32-kv tiles, 24KB LDS) ----------------
// grid 512: bh = (bid&7)*8 + ((bid>>3)&7), qt = bid>>6 (0..7, q-tile 128).
// 4 waves x 32 q (g=2). 32 KV tiles of 32, double-buffered via global_load_lds.
__global__ __launch_bounds__(256, 4) void attn(
    const ushort_t* __restrict__ Qg,
    const ushort_t* __restrict__ KVg,
    ushort_t* __restrict__ Oc)
{
  __shared__ __align__(16) short KVl[2][6144];   // [buf][K 3072 | V 3072]

  const int bid = blockIdx.x;
  const int bh = (bid & 7)*8 + ((bid >> 3) & 7);
  const int qt = bid >> 6;                      // 0..7
  const int tid = threadIdx.x;
  const int w = tid >> 6, lane = tid & 63;
  const int lo = lane & 15, hi = lane >> 4;
  const size_t qbase  = (size_t)bh * 16 * 6144;
  const size_t kvbase = (size_t)bh * 32 * 6144;

  // Q fragments (B-operand), frag-order lane-linear loads
  bf16x8 qf[2][3];
  #pragma unroll
  for (int g = 0; g < 2; ++g){
    int qq = qt*128 + w*32 + g*16;
    const ushort_t* qb = Qg + qbase + (size_t)(qq >> 6)*6144 + (size_t)(((qq>>4)&3)*3)*512;
    #pragma unroll
    for (int c = 0; c < 3; ++c)
      qf[g][c] = *(const bf16x8*)(qb + (c*64 + lane)*8);
  }

  f32x4 acc[6][2];
  #pragma unroll
  for (int ft = 0; ft < 6; ++ft){ acc[ft][0] = (f32x4){0,0,0,0}; acc[ft][1] = (f32x4){0,0,0,0}; }
  float lr[2] = {0.f, 0.f};

#define STAGE(tt, bb) do { \
    const ushort_t* kv_ = KVg + kvbase + (size_t)(tt)*6144 + tid*8; \
    short* l_ = &KVl[bb][tid*8]; \
    gll16(kv_, l_); gll16(kv_ + 2048, l_ + 2048); gll16(kv_ + 4096, l_ + 4096); \
  } while(0)

  STAGE(0, 0);
  __syncthreads();

  for (int t = 0; t < 32; ++t){
    if (t < 31) STAGE(t+1, (t+1)&1);
    const int cb = t & 1;

    // QK^T (swapped): st[g][kvb][r] = S^T[kv=16kvb+4hi+r][q]
    f32x4 st[2][2];
    __builtin_amdgcn_s_setprio(1);
    #pragma unroll
    for (int kvb = 0; kvb < 2; ++kvb){
      bf16x8 kf[3];
      #pragma unroll
      for (int c = 0; c < 3; ++c)
        kf[c] = *(const bf16x8*)&KVl[cb][((kvb*3 + c)*64 + lane)*8];
      #pragma unroll
      for (int g = 0; g < 2; ++g){
        f32x4 s = {0.f,0.f,0.f,0.f};
        #pragma unroll
        for (int c = 0; c < 3; ++c)
          s = __builtin_amdgcn_mfma_f32_16x16x32_bf16(kf[c], qf[g][c], s, 0, 0, 0);
        st[g][kvb] = s;
      }
    }
    __builtin_amdgcn_s_setprio(0);

    // no-max softmax: p = exp2(s); lane-partial denominator; pack own regs
    bf16x8 pb[2];
    #pragma unroll
    for (int g = 0; g < 2; ++g){
      #pragma unroll
      for (int kvb = 0; kvb < 2; ++kvb)
        #pragma unroll
        for (int r = 0; r < 4; ++r){ st[g][kvb][r] = exp2x(st[g][kvb][r]); lr[g] += st[g][kvb][r]; }
      union { uint32_t u[4]; bf16x8 v; } pu;
      pu.u[0] = pk2bf(st[g][0][0], st[g][0][1]);
      pu.u[1] = pk2bf(st[g][0][2], st[g][0][3]);
      pu.u[2] = pk2bf(st[g][1][0], st[g][1][1]);
      pu.u[3] = pk2bf(st[g][1][2], st[g][1][3]);
      pb[g] = pu.v;
    }

    // PV: O^T[f][q] += V^T-frag (pi-order) x P-frag (own regs)
    __builtin_amdgcn_s_setprio(1);
    #pragma unroll
    for (int ft = 0; ft < 6; ++ft){
      bf16x8 va = *(const bf16x8*)&KVl[cb][3072 + (ft*64 + lane)*8];
      acc[ft][0] = __builtin_amdgcn_mfma_f32_16x16x32_bf16(va, pb[0], acc[ft][0], 0, 0, 0);
      acc[ft][1] = __builtin_amdgcn_mfma_f32_16x16x32_bf16(va, pb[1], acc[ft][1], 0, 0, 0);
    }
    __builtin_amdgcn_s_setprio(0);

    __syncthreads();
  }
#undef STAGE

  // epilogue: reduce l across lane groups; Oc frag layout
  #pragma unroll
  for (int g = 0; g < 2; ++g){
    float l = lr[g];
    l += __shfl_xor(l, 16);
    l += __shfl_xor(l, 32);
    float rl = 1.f / l;
    int q = qt*128 + w*32 + g*16 + lo;
    #pragma unroll
    for (int ft = 0; ft < 6; ++ft){
      uint2 o;
      o.x = pk2bf(acc[ft][g][0]*rl, acc[ft][g][1]*rl);
      o.y = pk2bf(acc[ft][g][2]*rl, acc[ft][g][3]*rl);
      size_t ad = ((size_t)(bh*24 + ft*4 + hi)*1024 + q)*4;
      *(uint2*)(Oc + ad) = o;
    }
  }
}

// ---------------- Kernel C: output projection ----------------
__global__ __launch_bounds__(256) void out_proj(
    const ushort_t* __restrict__ Oc,
    const ushort_t* __restrict__ Wb4,
    float* __restrict__ out)
{
  const int tile = blockIdx.x;
  const int rr = tile >> 7, rt = tile & 127;
  int i, dx, d; rr_decode(rr, i, dx, d); (void)dx; (void)d;

  const int lane = threadIdx.x & 63;
  const int w    = threadIdx.x >> 6;
  const int lo = lane & 15, hi = lane >> 4;

  bf16x8 afr[2];
  {
    const int R = rt*64 + w*16 + lo;
    const int b = R >> 10, s = R & 1023;
    union { uint2 u2[2]; bf16x8 v; } a0, a1;
    #pragma unroll
    for (int jj = 0; jj < 2; ++jj){
      a0.u2[jj] = *(const uint2*)(Oc + ((size_t)((b*8 + hi)*24 + 2*rr + jj)*1024 + s)*4);
      a1.u2[jj] = *(const uint2*)(Oc + ((size_t)((b*8 + 4 + hi)*24 + 2*rr + jj)*1024 + s)*4);
    }
    afr[0] = a0.v;
    afr[1] = a1.v;
  }

  const ushort_t* Wb = Wb4 + (size_t)3*28672 + (size_t)i * 4096;
  #pragma unroll
  for (int ot = 0; ot < 4; ++ot){
    f32x4 acc = {0.f,0.f,0.f,0.f};
    #pragma unroll
    for (int c = 0; c < 2; ++c){
      bf16x8 bfr = *(const bf16x8*)(Wb + (size_t)(lo + 16*ot) * 64 + 32*c + 8*hi);
      acc = __builtin_amdgcn_mfma_f32_16x16x32_bf16(afr[c], bfr, acc, 0, 0, 0);
    }
    #pragma unroll
    for (int r = 0; r < 4; ++r){
      int bs = rt*64 + w*16 + hi*4 + r;
      out[(size_t)(bs*12 + rr)*64 + lo + 16*ot] = acc[r];
    }
  }
}

extern "C" void kernel_launch(void* const* d_in, const int* in_sizes, int n_in,
                              void* d_out, int out_size, void* d_ws, size_t ws_size,
                              hipStream_t stream)
{
  const float* xA1 = (const float*)d_in[0];
  const float* xB2 = (const float*)d_in[1];
  const float* xE1 = (const float*)d_in[2];
  const float* xE2 = (const float*)d_in[3];
  const float* xE3 = (const float*)d_in[4];
  const float* xE4 = (const float*)d_in[5];
  const float* xE5 = (const float*)d_in[6];
  const float* Wq  = (const float*)d_in[7];
  const float* Wk  = (const float*)d_in[8];
  const float* Wv  = (const float*)d_in[9];
  const float* Wo  = (const float*)d_in[10];

  ushort_t* Qg  = (ushort_t*)d_ws;
  ushort_t* KVg = Qg + NE;                  // 2*NE (K+V interleaved, 32-kv groups)
  ushort_t* Oc  = KVg + (size_t)2*NE;
  ushort_t* Wb4 = Oc + NE;                  // 4*28672 bf16

  wconv<<<dim3(14,4), dim3(256), 0, stream>>>(Wq, Wk, Wv, Wo, Wb4);
  qkv_proj<<<dim3(1536), dim3(256), 0, stream>>>(xA1,xB2,xE1,xE2,xE3,xE4,xE5,
                                                 Wb4, Qg, KVg);
  attn<<<dim3(512), dim3(256), 0, stream>>>(Qg, KVg, Oc);
  out_proj<<<dim3(1536), dim3(256), 0, stream>>>(Oc, Wb4, (float*)d_out);
}